// Round 8
// baseline (456.706 us; speedup 1.0000x reference)
//
#include <hip/hip_runtime.h>
#include <cstdint>

#define N 8192
#define FIN 256
#define FOUT 128
#define ALPHA 0.2f
#define JP 4                  // j-split
#define JSL (N / JP)          // 2048 j per block
#define TJ 64                 // j-tile
#define NTILE (JSL / TJ)      // 32 tiles
#define RB 32                 // rows per block

typedef unsigned short u16;
typedef __attribute__((ext_vector_type(8))) short short8;
typedef __attribute__((ext_vector_type(4))) float floatx4;

__device__ __forceinline__ u16 bf16_rne(float f) {
  uint32_t u = __float_as_uint(f);
  u += 0x7fff + ((u >> 16) & 1);
  return (u16)(u >> 16);
}

__device__ __forceinline__ void gl_lds16(const void* g, void* l) {
  __builtin_amdgcn_global_load_lds(
      (const __attribute__((address_space(1))) void*)g,
      (__attribute__((address_space(3))) void*)l, 16, 0, 0);
}

// ---------------------------------------------------------------------------
// Kernel 1: h = x@W (fp32); hT3 bf16 tiled [jb][nt][m*4+q][8]; src/dst.
// (unchanged from round 7)
// ---------------------------------------------------------------------------
__global__ __launch_bounds__(256) void k_proj(const float* __restrict__ x,
                                              const float* __restrict__ W,
                                              const float* __restrict__ a,
                                              u16* __restrict__ hT3,
                                              float* __restrict__ srcv,
                                              float* __restrict__ dstv) {
  __shared__ float xs[8 * FIN];
  __shared__ float partS[4][4], partD[4][4];
  const int t = threadIdx.x;
  const int R0 = blockIdx.x * 8;

  const float4* xv = (const float4*)(x + (size_t)R0 * FIN);
  float4* xsv = (float4*)xs;
  xsv[t] = xv[t];
  xsv[t + 256] = xv[t + 256];
  __syncthreads();

  const int c  = t & 127;
  const int rg = (t >> 7) * 4;

  float acc[4] = {0.f, 0.f, 0.f, 0.f};
  float wa[4], wb[4];
  #pragma unroll
  for (int j = 0; j < 4; ++j) wa[j] = W[j * FOUT + c];
  #pragma unroll
  for (int j = 0; j < 4; ++j) wb[j] = W[(4 + j) * FOUT + c];

  for (int k4 = 0; k4 < FIN / 4; ++k4) {
    float wc[4];
    #pragma unroll
    for (int j = 0; j < 4; ++j) { wc[j] = wa[j]; wa[j] = wb[j]; }
    const int kn = (k4 + 2 < FIN / 4) ? k4 + 2 : k4;
    #pragma unroll
    for (int j = 0; j < 4; ++j) wb[j] = W[(kn * 4 + j) * FOUT + c];
    #pragma unroll
    for (int i = 0; i < 4; ++i) {
      const float4 xq = *(const float4*)&xs[(rg + i) * FIN + k4 * 4];
      acc[i] += xq.x * wc[0] + xq.y * wc[1] + xq.z * wc[2] + xq.w * wc[3];
    }
  }

  {
    const int j = R0 + rg;
    const int jb = j >> 5, q = (j >> 3) & 3, jj = j & 7;
    const int m = c & 15, nt = c >> 4;
    union { u16 u[4]; uint2 v; } pk;
    #pragma unroll
    for (int i = 0; i < 4; ++i) pk.u[i] = bf16_rne(acc[i]);
    *(uint2*)(hT3 + (size_t)(((jb * 8 + nt) * 64) + (m * 4 + q)) * 8 + jj) = pk.v;
  }

  const float a1 = a[c], a2 = a[FOUT + c];
  float s4[4], d4[4];
  #pragma unroll
  for (int i = 0; i < 4; ++i) { s4[i] = acc[i] * a1; d4[i] = acc[i] * a2; }
  #pragma unroll
  for (int off = 32; off > 0; off >>= 1) {
    #pragma unroll
    for (int i = 0; i < 4; ++i) {
      s4[i] += __shfl_down(s4[i], off);
      d4[i] += __shfl_down(d4[i], off);
    }
  }
  const int wv = t >> 6, lane = t & 63;
  if (lane == 0) {
    #pragma unroll
    for (int i = 0; i < 4; ++i) { partS[wv][i] = s4[i]; partD[wv][i] = d4[i]; }
  }
  __syncthreads();
  if (t < 16) {
    const int i = t & 3, rg2 = (t >> 2) & 1, which = t >> 3;
    if (which == 0) srcv[R0 + rg2 * 4 + i] = partS[rg2*2][i] + partS[rg2*2+1][i];
    else            dstv[R0 + rg2 * 4 + i] = partD[rg2*2][i] + partD[rg2*2+1][i];
  }
}

// ---------------------------------------------------------------------------
// Kernel 2: hybrid fused GAT — ONE barrier per 64-j tile.
// b-frags: double-buffered LDS via global_load_lds (vmcnt drained only at B1,
// one full tile of cover). A-frags: computed per-lane in registers (lane(q,m)
// = p[row m][q*8..+8], the MFMA A layout) — no S tile, no second barrier
// (round 7's B2 sat ~200 cyc after the DMA+adj issue and drained them every
// tile -> full HBM latency exposed per tile). Waves: 2 row-groups x 2
// col-halves (p duplicated per col-half: 16 extra exp/lane/tile beats an LDS
// round-trip + barrier). adj/dst prefetched distance-1 in NAMED reg sets,
// 2x-unrolled loop alternates sets (no moves, no dynamic indexing).
// Grid: bm(0..255) | jp<<8 -> 1024 blocks, 4/CU (33 KB LDS).
// ---------------------------------------------------------------------------
__global__ __launch_bounds__(256, 4) void k_gat(const int* __restrict__ adj,
                                                const u16* __restrict__ hT3,
                                                const float* __restrict__ srcv,
                                                const float* __restrict__ dstv,
                                                float* __restrict__ P,
                                                float* __restrict__ lp) {
  __shared__ u16 hS[2][8192];      // 2 x 16 KB staged hT tiles
  const int t = threadIdx.x;
  const int wv = t >> 6, lane = t & 63;
  const int q = lane >> 4, m = lane & 15;
  const int rg = wv & 1;           // row-group (16 rows)
  const int cg = wv >> 1;          // col-half (64 cols)
  const int bm = blockIdx.x & 255;
  const int jp = blockIdx.x >> 8;
  const int R0 = bm * RB;
  const int j0 = jp * JSL;
  const int Lq = m * 4 + q;

  const float srcm = srcv[R0 + rg * 16 + m];
  const int*   adjp = adj + (size_t)(R0 + rg * 16 + m) * N + j0 + q * 8;
  const float* dstp = dstv + j0 + q * 8;
  const size_t jb00 = (size_t)(j0 >> 5);

  floatx4 acc[4];
  #pragma unroll
  for (int nt = 0; nt < 4; ++nt) acc[nt] = (floatx4){0.f, 0.f, 0.f, 0.f};
  float lsum = 0.f;

  // DMA tile I into hS[BUF]: 16 chunks of 1 KB, wave wv stages 4
  #define STAGE(I, BUF)                                                        \
  {                                                                            \
    _Pragma("unroll")                                                          \
    for (int cc = 0; cc < 4; ++cc) {                                           \
      const int kc = wv * 4 + cc;                                              \
      const int jbl = kc >> 3, nt_ = kc & 7;                                   \
      const u16* srcp = hT3 + ((jb00 + (size_t)(I) * 2 + jbl) * 8 + nt_) * 512 \
                        + (size_t)lane * 8;                                    \
      gl_lds16(srcp, &hS[BUF][kc * 512]);                                      \
    }                                                                          \
  }

  // one tile body: B1 -> prefetch(i+1 into NXT regs) -> DMA(i+1 -> BUFW) ->
  // p(i from CUR regs) -> MFMA(i from hS[BUFR])
  #define TILE_BODY(I, BUFR, BUFW,                                             \
                    CA0, CA1, CA2, CA3, CD0, CD1, CD2, CD3,                    \
                    NA0, NA1, NA2, NA3, ND0, ND1, ND2, ND3)                    \
  {                                                                            \
    __syncthreads();  /* B1: drains DMA(I)+prefetch(I); frees hS[BUFW] */      \
    const int nx = ((I) + 1 < NTILE) ? (I) + 1 : (I);                          \
    NA0 = *(const int4*)(adjp + nx * TJ);                                      \
    NA1 = *(const int4*)(adjp + nx * TJ + 4);                                  \
    NA2 = *(const int4*)(adjp + nx * TJ + 32);                                 \
    NA3 = *(const int4*)(adjp + nx * TJ + 36);                                 \
    ND0 = *(const float4*)(dstp + nx * TJ);                                    \
    ND1 = *(const float4*)(dstp + nx * TJ + 4);                                \
    ND2 = *(const float4*)(dstp + nx * TJ + 32);                               \
    ND3 = *(const float4*)(dstp + nx * TJ + 36);                               \
    STAGE(nx, BUFW)                                                            \
    _Pragma("unroll")                                                          \
    for (int ks = 0; ks < 2; ++ks) {                                           \
      const int4   A0 = ks ? CA2 : CA0, A1 = ks ? CA3 : CA1;                   \
      const float4 D0 = ks ? CD2 : CD0, D1 = ks ? CD3 : CD1;                   \
      const int   ai[8] = {A0.x, A0.y, A0.z, A0.w, A1.x, A1.y, A1.z, A1.w};    \
      const float df[8] = {D0.x, D0.y, D0.z, D0.w, D1.x, D1.y, D1.z, D1.w};    \
      union { u16 u[8]; short8 s; } pk;                                        \
      _Pragma("unroll")                                                        \
      for (int e = 0; e < 8; ++e) {                                            \
        float v = srcm + df[e];                                                \
        v = fmaxf(v, ALPHA * v);                                               \
        const float p = ai[e] > 0 ? __expf(v) : 0.f;                           \
        lsum += p;                                                             \
        pk.u[e] = bf16_rne(p);                                                 \
      }                                                                        \
      _Pragma("unroll")                                                        \
      for (int nt = 0; nt < 4; ++nt) {                                         \
        const short8 bf =                                                      \
            *(const short8*)&hS[BUFR][(ks * 8 + cg * 4 + nt) * 512 + Lq * 8];  \
        acc[nt] =                                                              \
            __builtin_amdgcn_mfma_f32_16x16x32_bf16(pk.s, bf, acc[nt], 0, 0, 0); \
      }                                                                        \
    }                                                                          \
  }

  // prologue: tile 0 -> set A regs + hS[0]
  int4   aA0 = *(const int4*)(adjp),      aA1 = *(const int4*)(adjp + 4);
  int4   aA2 = *(const int4*)(adjp + 32), aA3 = *(const int4*)(adjp + 36);
  float4 dA0 = *(const float4*)(dstp),      dA1 = *(const float4*)(dstp + 4);
  float4 dA2 = *(const float4*)(dstp + 32), dA3 = *(const float4*)(dstp + 36);
  STAGE(0, 0)
  int4   aB0, aB1, aB2, aB3;
  float4 dB0, dB1, dB2, dB3;

  for (int i = 0; i < NTILE; i += 2) {
    TILE_BODY(i,     (i >> 1) & 0 ? 1 : 0, 1,   // read hS[0], write hS[1]
              aA0, aA1, aA2, aA3, dA0, dA1, dA2, dA3,
              aB0, aB1, aB2, aB3, dB0, dB1, dB2, dB3)
    TILE_BODY(i + 1, 1, 0,                      // read hS[1], write hS[0]
              aB0, aB1, aB2, aB3, dB0, dB1, dB2, dB3,
              aA0, aA1, aA2, aA3, dA0, dA1, dA2, dA3)
  }
  #undef TILE_BODY
  #undef STAGE

  // row-sum over the 4 q-lanes sharing row m (only col-half 0 publishes)
  lsum += __shfl_xor(lsum, 16);
  lsum += __shfl_xor(lsum, 32);
  if (cg == 0 && lane < 16)
    lp[(size_t)jp * N + R0 + rg * 16 + lane] = lsum;

  // partial store: rows R0+rg*16+(q*4+ri), cols cg*64 + nt*16 + m
  float* Pp = P + ((size_t)jp * N + R0 + rg * 16) * FOUT + cg * 64;
  #pragma unroll
  for (int nt = 0; nt < 4; ++nt)
    #pragma unroll
    for (int ri = 0; ri < 4; ++ri)
      Pp[(size_t)(q * 4 + ri) * FOUT + nt * 16 + m] = acc[nt][ri];
}

// ---------------------------------------------------------------------------
// Kernel 3: sum JP partials, normalize by row-sum.
// ---------------------------------------------------------------------------
__global__ __launch_bounds__(256) void k_norm(const float* __restrict__ P,
                                              const float* __restrict__ lp,
                                              float* __restrict__ out) {
  const int idx = blockIdx.x * 256 + threadIdx.x;
  const int rr = idx >> 5;
  const int c4 = (idx & 31) * 4;
  float l = 0.f;
  #pragma unroll
  for (int j = 0; j < JP; ++j) l += lp[j * N + rr];
  const float inv = 1.0f / l;
  float4 s = {0.f, 0.f, 0.f, 0.f};
  #pragma unroll
  for (int j = 0; j < JP; ++j) {
    const float4 p = *(const float4*)(P + ((size_t)j * N + rr) * FOUT + c4);
    s.x += p.x; s.y += p.y; s.z += p.z; s.w += p.w;
  }
  s.x *= inv; s.y *= inv; s.z *= inv; s.w *= inv;
  *(float4*)(out + (size_t)rr * FOUT + c4) = s;
}

extern "C" void kernel_launch(void* const* d_in, const int* in_sizes, int n_in,
                              void* d_out, int out_size, void* d_ws, size_t ws_size,
                              hipStream_t stream) {
  const float* x   = (const float*)d_in[0];
  const int*   adj = (const int*)d_in[1];
  const float* W   = (const float*)d_in[2];
  const float* a   = (const float*)d_in[3];
  float* out = (float*)d_out;

  char* ws = (char*)d_ws;
  u16*   hT3  = (u16*)ws;     ws += (size_t)FOUT * N * sizeof(u16);            // 2 MB
  float* srcv = (float*)ws;   ws += (size_t)N * sizeof(float);
  float* dstv = (float*)ws;   ws += (size_t)N * sizeof(float);
  float* P    = (float*)ws;   ws += (size_t)JP * N * FOUT * sizeof(float);     // 16 MB
  float* lp   = (float*)ws;   ws += (size_t)JP * N * sizeof(float);

  k_proj<<<N / 8, 256, 0, stream>>>(x, W, a, hT3, srcv, dstv);
  k_gat <<<256 * JP, 256, 0, stream>>>(adj, hT3, srcv, dstv, P, lp);
  k_norm<<<(N * FOUT / 4) / 256, 256, 0, stream>>>(P, lp, out);
}